// Round 8
// baseline (222.769 us; speedup 1.0000x reference)
//
#include <hip/hip_runtime.h>
#include <hip/hip_bf16.h>
#include <stdint.h>

// LoRA int8-dequant linear, MI355X/gfx950 — int8 main path, 2 blocks/CU.
//   Xi8[8192][4096] = rne(x * 127/absmax_row),  tstep[m] = absmax_row/127
//   Wi8[4096][4096] = qweight codes (exact i8)
//   out = (Xi8 @ Wi8^T)_i32 * (tstep[m]*scale[o]) + xa @ (2B)^T
// Main GEMM: 128x256 tile, BK=64, 8 waves x (64x64), mfma_i32_16x16x64_i8,
// 3-deep LDS (72 KB) -> 2 blocks/CU co-resident (overlap via occupancy),
// counted vmcnt(3), i8 XOR swizzle, 1 barrier/K-tile.

typedef __bf16 bf16x8 __attribute__((ext_vector_type(8)));
typedef float f32x4 __attribute__((ext_vector_type(4)));
typedef int i32x4 __attribute__((ext_vector_type(4)));

#define DIN   4096
#define DOUT  4096
#define MTOT  8192
#define RNK   64
#define NT    64
#define BUFB  24576   // 24 KB per LDS buffer (A 8K + B 16K)

__device__ inline void gload_lds16(const void* g, void* l) {
  __builtin_amdgcn_global_load_lds((const __attribute__((address_space(1))) void*)g,
                                   (__attribute__((address_space(3))) void*)l,
                                   16, 0, 0);
}

// ---- per-row absmax quantize x -> i8 (RNE), record step ----
__global__ __launch_bounds__(256) void quant_x_kernel(const float* __restrict__ x,
                                                      signed char* __restrict__ Xi8,
                                                      float* __restrict__ tstep) {
  const int row = blockIdx.x, t = threadIdx.x;
  const float4* xr = (const float4*)(x + (size_t)row * DIN);
  float4 v[4];
  float m = 0.f;
#pragma unroll
  for (int s = 0; s < 4; ++s) {
    v[s] = xr[t + s * 256];
    m = fmaxf(m, fmaxf(fmaxf(fabsf(v[s].x), fabsf(v[s].y)),
                       fmaxf(fabsf(v[s].z), fabsf(v[s].w))));
  }
#pragma unroll
  for (int off = 32; off > 0; off >>= 1) m = fmaxf(m, __shfl_xor(m, off));
  __shared__ float wm[4];
  if ((t & 63) == 0) wm[t >> 6] = m;
  __syncthreads();
  m = fmaxf(fmaxf(wm[0], wm[1]), fmaxf(wm[2], wm[3]));
  m = fmaxf(m, 1e-30f);
  const float rs = 127.0f / m;
  int* orow = (int*)(Xi8 + (size_t)row * DIN);
#pragma unroll
  for (int s = 0; s < 4; ++s) {
    float e[4] = {v[s].x, v[s].y, v[s].z, v[s].w};
    union { signed char c[4]; int i; } p;
#pragma unroll
    for (int j = 0; j < 4; ++j) {
      int q = __float2int_rn(e[j] * rs);
      q = q > 127 ? 127 : (q < -127 ? -127 : q);
      p.c[j] = (signed char)q;
    }
    orow[t + s * 256] = p.i;
  }
  if (t == 0) tstep[row] = m * (1.0f / 127.0f);
}

// ---- qweight int32 codes -> i8 ----
__global__ void cvt_w_kernel(const int* __restrict__ q, signed char* __restrict__ Wi8) {
  int i = blockIdx.x * blockDim.x + threadIdx.x;
  int4 v = ((const int4*)q)[i];
  union { signed char c[4]; int i; } p;
  p.c[0] = (signed char)v.x; p.c[1] = (signed char)v.y;
  p.c[2] = (signed char)v.z; p.c[3] = (signed char)v.w;
  ((int*)Wi8)[i] = p.i;
}

// ---- blocks 0..63: quantize lora_A rows -> Ai8/astep; 64..319: 2*lora_B -> Blt bf16 ----
__global__ __launch_bounds__(256) void cvt_ab_kernel(const float* __restrict__ A,
                                                     const float* __restrict__ B,
                                                     signed char* __restrict__ Ai8,
                                                     float* __restrict__ astep,
                                                     __bf16* __restrict__ Blt) {
  const int t = threadIdx.x;
  if (blockIdx.x < 64) {
    const int row = blockIdx.x;
    const float4* ar = (const float4*)(A + (size_t)row * DIN);
    float4 v[4];
    float m = 0.f;
#pragma unroll
    for (int s = 0; s < 4; ++s) {
      v[s] = ar[t + s * 256];
      m = fmaxf(m, fmaxf(fmaxf(fabsf(v[s].x), fabsf(v[s].y)),
                         fmaxf(fabsf(v[s].z), fabsf(v[s].w))));
    }
#pragma unroll
    for (int off = 32; off > 0; off >>= 1) m = fmaxf(m, __shfl_xor(m, off));
    __shared__ float wm[4];
    if ((t & 63) == 0) wm[t >> 6] = m;
    __syncthreads();
    m = fmaxf(fmaxf(wm[0], wm[1]), fmaxf(wm[2], wm[3]));
    m = fmaxf(m, 1e-30f);
    const float rs = 127.0f / m;
    int* orow = (int*)(Ai8 + (size_t)row * DIN);
#pragma unroll
    for (int s = 0; s < 4; ++s) {
      float e[4] = {v[s].x, v[s].y, v[s].z, v[s].w};
      union { signed char c[4]; int i; } p;
#pragma unroll
      for (int j = 0; j < 4; ++j) {
        int q = __float2int_rn(e[j] * rs);
        q = q > 127 ? 127 : (q < -127 ? -127 : q);
        p.c[j] = (signed char)q;
      }
      orow[t + s * 256] = p.i;
    }
    if (t == 0) astep[row] = m * (1.0f / 127.0f);
  } else {
    int i = (blockIdx.x - 64) * 256 + t;
    float4 v = ((const float4*)B)[i];
    union { __bf16 h[4]; uint64_t u; } p;
    p.h[0] = (__bf16)(2.0f * v.x); p.h[1] = (__bf16)(2.0f * v.y);
    p.h[2] = (__bf16)(2.0f * v.z); p.h[3] = (__bf16)(2.0f * v.w);
    ((uint64_t*)Blt)[i] = p.u;
  }
}

// ---- xa = (Xi8 @ Ai8^T)*tstep*astep -> bf16 [8192][64] ----
__global__ __launch_bounds__(128) void lora_xa_kernel(const signed char* __restrict__ Xi8,
                                                      const float* __restrict__ tstep,
                                                      const signed char* __restrict__ Ai8,
                                                      const float* __restrict__ astep,
                                                      __bf16* __restrict__ xa) {
  int wid = threadIdx.x >> 6, lane = threadIdx.x & 63;
  int rowbase = blockIdx.x * 32 + wid * 16;
  i32x4 acc[4] = {};
  const signed char* xrow = Xi8 + (size_t)(rowbase + (lane & 15)) * DIN + (lane >> 4) * 16;
  const signed char* ab = Ai8 + (size_t)(lane & 15) * DIN + (lane >> 4) * 16;
  for (int k0 = 0; k0 < DIN; k0 += 64) {
    i32x4 af = *(const i32x4*)(xrow + k0);
#pragma unroll
    for (int ni = 0; ni < 4; ++ni) {
      i32x4 bv = *(const i32x4*)(ab + (size_t)ni * 16 * DIN + k0);
      acc[ni] = __builtin_amdgcn_mfma_i32_16x16x64_i8(af, bv, acc[ni], 0, 0, 0);
    }
  }
  f32x4 tm = *(const f32x4*)&tstep[rowbase + (lane >> 4) * 4];
#pragma unroll
  for (int ni = 0; ni < 4; ++ni) {
    const int col = ni * 16 + (lane & 15);
    const float as = astep[col];
#pragma unroll
    for (int j = 0; j < 4; ++j) {
      int row = rowbase + (lane >> 4) * 4 + j;
      xa[(size_t)row * RNK + col] = (__bf16)((float)acc[ni][j] * tm[j] * as);
    }
  }
}

// ==== i8 main GEMM: 128x256 tile, 8 waves x 64x64, 3-deep LDS, 2 blocks/CU ====
// LDS 72 KB: 3 bufs x 24 KB, buf = { A(8K: 128 rows x 64 i8), B(16K: 256 x 64) }.
// Row r, logical 16B-slot s at phys slot s ^ ((r>>1)&3) (conflict-free).
// Body(kt): stage(kt+2)->buf[(kt+2)%3] (3 loads/thread); ds_read a[4]+b[4];
// MFMA 16; vmcnt(3) [tile kt+1 landed]; barrier. Tail: kt=62 no stage +
// vmcnt(0); kt=63 bare. Overlap comes from the co-resident second block.
__global__ __launch_bounds__(512, 4) void gemm_i8_kernel(const signed char* __restrict__ Xi8,
                                                         const signed char* __restrict__ Wi8,
                                                         const float* __restrict__ scale,
                                                         const float* __restrict__ tstep,
                                                         const __bf16* __restrict__ xa,
                                                         const __bf16* __restrict__ Blt,
                                                         float* __restrict__ out) {
  extern __shared__ char smem[];
  const int tid = threadIdx.x;
  const int lane = tid & 63;
  const int w = tid >> 6;
  const int wr = w >> 2;         // 0..1 -> rows wr*64
  const int wc = w & 3;          // 0..3 -> cols wc*64

  // bijective XCD swizzle (nwg=1024, 1024%8==0)
  const int swz = (blockIdx.x & 7) * 128 + (blockIdx.x >> 3);
  const int bx = swz & 15;       // N tile 0..15 (256 cols)
  const int by = swz >> 4;       // M tile 0..63 (128 rows)
  const size_t bm = (size_t)by * 128, bn = (size_t)bx * 256;

  // read swizzle: frag row base + (lane&15), logical 16B-slot (lane>>4)
  const int rc = ((lane >> 4) ^ ((lane >> 1) & 3)) << 4;
  // stage constants: thread t -> LDS byte t*16 (row t>>2, phys slot t&3)
  const int srow = tid >> 2;
  const int scol = ((tid & 3) ^ ((tid >> 3) & 3)) << 4;

  auto SH = [&](const signed char* g, size_t r0, int srct, int ldsoff) {
    gload_lds16(g + (r0 + srow) * (size_t)4096 + srct * 64 + scol,
                smem + ldsoff + tid * 16);
  };
  auto stage = [&](int srct, int buf) {
    int b = buf * BUFB;
    SH(Xi8, bm, srct, b);                 // A: 128 rows, 8 KB
    SH(Wi8, bn, srct, b + 8192);          // B rows 0-127
    SH(Wi8, bn + 128, srct, b + 16384);   // B rows 128-255
  };

  const int aoff = (wr * 64 + (lane & 15)) * 64 + rc;
  const int boff = 8192 + (wc * 64 + (lane & 15)) * 64 + rc;

  i32x4 a[4], b[4];
  i32x4 acc[4][4] = {};

  // prologue: tiles 0,1; vmcnt(3) -> tile 0 landed
  stage(0, 0); stage(1, 1);
  asm volatile("s_waitcnt vmcnt(3)" ::: "memory");
  __builtin_amdgcn_s_barrier();

  int cur = 0;
  for (int kt = 0; kt < NT; ++kt) {
    const int bufb = cur * BUFB;
    if (kt < NT - 2) {
      int sb = cur + 2; if (sb >= 3) sb -= 3;
      stage(kt + 2, sb);
    }
#pragma unroll
    for (int mi = 0; mi < 4; ++mi)
      a[mi] = *(const i32x4*)(smem + bufb + aoff + mi * 1024);
#pragma unroll
    for (int ni = 0; ni < 4; ++ni)
      b[ni] = *(const i32x4*)(smem + bufb + boff + ni * 1024);
    __builtin_amdgcn_s_setprio(1);
#pragma unroll
    for (int mi = 0; mi < 4; ++mi)
#pragma unroll
      for (int ni = 0; ni < 4; ++ni)
        acc[mi][ni] = __builtin_amdgcn_mfma_i32_16x16x64_i8(a[mi], b[ni], acc[mi][ni], 0, 0, 0);
    __builtin_amdgcn_s_setprio(0);
    __builtin_amdgcn_sched_barrier(0);
    if (kt < NT - 2) { asm volatile("s_waitcnt vmcnt(3)" ::: "memory"); }
    else if (kt == NT - 2) { asm volatile("s_waitcnt vmcnt(0)" ::: "memory"); }
    __builtin_amdgcn_s_barrier();
    ++cur; if (cur >= 3) cur = 0;
  }

  // ---- epilogue: stage xa (16 KB @0) / Blt (32 KB @16384) as bf16 rows of 128B ----
  const int sl_row = lane >> 3;
  const int sl_col = ((lane & 7) ^ (lane >> 3)) << 4;
  auto SBF = [&](const __bf16* g, size_t r0, int ldsoff) {
    char* d0 = smem + ldsoff + w * 2048 + lane * 16;
#pragma unroll
    for (int s = 0; s < 2; ++s) {
      const int rl = (w * 2 + s) * 8 + sl_row;
      gload_lds16((const char*)g + (r0 + rl) * 128 + sl_col, d0 + s * 1024);
    }
  };
  SBF(xa, bm, 0);
  SBF(Blt, bn, 16384); SBF(Blt, bn + 128, 32768);

  float sc[4];
#pragma unroll
  for (int ni = 0; ni < 4; ++ni)
    sc[ni] = scale[bn + wc * 64 + ni * 16 + (lane & 15)];

  asm volatile("s_waitcnt vmcnt(0)" ::: "memory");
  __builtin_amdgcn_s_barrier();

  const int cx0 = ((lane >> 4) << 4) ^ ((lane & 7) << 4);
  const int cx1 = (64 | ((lane >> 4) << 4)) ^ ((lane & 7) << 4);
  const int bltbase = 16384 + (wc >> 1) * 16384 + ((wc & 1) * 64 + (lane & 15)) * 128;

#pragma unroll
  for (int mi = 0; mi < 4; ++mi) {
    const int axb = (wr * 64 + mi * 16 + (lane & 15)) * 128;
    bf16x8 ax0 = *(const bf16x8*)(smem + axb + cx0);
    bf16x8 ax1 = *(const bf16x8*)(smem + axb + cx1);
    const size_t row = bm + wr * 64 + mi * 16 + (lane >> 4) * 4;
    f32x4 tm = *(const f32x4*)&tstep[row];
#pragma unroll
    for (int ni = 0; ni < 4; ++ni) {
      bf16x8 bl0 = *(const bf16x8*)(smem + bltbase + ni * 2048 + cx0);
      bf16x8 bl1 = *(const bf16x8*)(smem + bltbase + ni * 2048 + cx1);
      f32x4 l = {0.f, 0.f, 0.f, 0.f};
      l = __builtin_amdgcn_mfma_f32_16x16x32_bf16(ax0, bl0, l, 0, 0, 0);
      l = __builtin_amdgcn_mfma_f32_16x16x32_bf16(ax1, bl1, l, 0, 0, 0);
      const size_t col = bn + wc * 64 + ni * 16 + (lane & 15);
#pragma unroll
      for (int j = 0; j < 4; ++j)
        out[(row + j) * DOUT + col] = (float)acc[mi][ni][j] * (sc[ni] * tm[j]) + l[j];
    }
  }
}

extern "C" void kernel_launch(void* const* d_in, const int* in_sizes, int n_in,
                              void* d_out, int out_size, void* d_ws, size_t ws_size,
                              hipStream_t stream) {
  const float* x = (const float*)d_in[0];
  const int* qw = (const int*)d_in[1];
  const float* scale = (const float*)d_in[2];
  const float* lA = (const float*)d_in[3];
  const float* lB = (const float*)d_in[4];
  float* out = (float*)d_out;

  char* ws = (char*)d_ws;
  signed char* Xi8 = (signed char*)ws;                              // 33.6 MB
  signed char* Wi8 = (signed char*)(ws + 33554432);                 // 16.8 MB
  __bf16* xa    = (__bf16*)(ws + 50331648);                         // 1.05 MB
  signed char* Ai8 = (signed char*)(ws + 51380224);                 // 0.26 MB
  __bf16* Blt   = (__bf16*)(ws + 51904512);                         // 0.52 MB
  float* tstep  = (float*)(ws + 52428800);                          // 32 KB
  float* astep  = (float*)(ws + 52461568);                          // 256 B

  hipFuncSetAttribute((const void*)gemm_i8_kernel,
                      hipFuncAttributeMaxDynamicSharedMemorySize, 3 * BUFB);

  quant_x_kernel<<<MTOT, 256, 0, stream>>>(x, Xi8, tstep);
  cvt_w_kernel<<<DOUT * (DIN / 4) / 256, 256, 0, stream>>>(qw, Wi8);
  cvt_ab_kernel<<<320, 256, 0, stream>>>(lA, lB, Ai8, astep, Blt);
  lora_xa_kernel<<<MTOT / 32, 128, 0, stream>>>(Xi8, tstep, Ai8, astep, xa);
  gemm_i8_kernel<<<(MTOT / 128) * (DOUT / 256), 512, 3 * BUFB, stream>>>(
      Xi8, Wi8, scale, tstep, xa, Blt, out);
}